// Round 6
// baseline (87.329 us; speedup 1.0000x reference)
//
#include <hip/hip_runtime.h>
#include <stdint.h>

#pragma clang fp contract(off)

#define NA 10
#define LL 4096
#define NB 4
#define NSEL (LL * NA)        // 40960 proposals per image
#define PRE2 2048             // NMS candidate window (prefix-stable: 300 kept << 2048)
#define POST_NMS 300
#define CAND 4096             // candidate buffer (threshold overshoot bound)
#define TWORDS 33792          // col-major mask words per image: 64 * sum_{w=0..31}(w+1)

__constant__ float c_WS[NA] = {16.f, 32.f, 40.f, 48.f, 64.f, 72.f, 80.f, 96.f, 112.f, 128.f};

// async global->LDS DMA: per-lane 16B from g (per-lane addr), lands at uniform dst + lane*16
__device__ inline void gload_lds16(const void* g, void* l) {
    __builtin_amdgcn_global_load_lds(
        (const __attribute__((address_space(1))) unsigned*)g,
        (__attribute__((address_space(3))) unsigned*)l, 16, 0, 0);
}

// ---------------- Kernel 1: fused decode + LDS histogram -> exact kmin -> compact ----------------
// Round-5 post-mortem: node overhead ~5us each; k_prep's only consumer is this kernel's
// histogram pass. Fuse: one 1024-thread block per image decodes 40960 elems (10 unrolled
// iters x 4 elems; iter == anchor so c_WS[it] is scalar and loads are coalesced 16B row
// reads, depth-2 register prefetch for MLP), writes packed+prop, histograms keys on the
// fly. Pass 2 compacts from the L1/L2-hot packed (same-CU write-through: coherent).
// Hist: 16-bit prefixes in 32K u32 words, two u16 counts each (max 40960 < 65536).
// Bucket k: p=k>>1, word=(p&31)*1024+(p>>5), half=k&1. Suffix-scan semantics identical
// to the round-5 verified kernel, so kmin is bit-identical.
__global__ __launch_bounds__(1024, 1) void k_select(const float* __restrict__ scores,
                                                    const float* __restrict__ deltas,
                                                    unsigned long long* __restrict__ packed,
                                                    float2* __restrict__ prop,
                                                    unsigned long long* __restrict__ cand,
                                                    int* __restrict__ gcnt) {
    __shared__ unsigned hist[32768];     // 128 KB
    __shared__ unsigned swsum[16];
    __shared__ unsigned sAfter;
    __shared__ int sSeg;
    __shared__ unsigned skmin;
    __shared__ int sCnt;

    const int tid = threadIdx.x;
    const int lane = tid & 63;
    const int wv = tid >> 6;
    const int b = blockIdx.x;

    if (tid == 0) sCnt = 0;
    {
        const uint4 z = make_uint4(0, 0, 0, 0);
        uint4* h4 = (uint4*)hist;
        #pragma unroll
        for (int i = 0; i < 8; ++i) h4[i * 1024 + tid] = z;
    }
    __syncthreads();

    // --- pass 1: decode + key pack + on-the-fly histogram (iter = anchor a) ---
    {
        const float4* sRow = (const float4*)scores;   // row it: index ((b*20+10+it)<<10)+tid
        const float4* dRow = (const float4*)deltas;
        float4 sc[2], da[2], db[2];
        #pragma unroll
        for (int pf = 0; pf < 2; ++pf) {              // preload it=0,1
            sc[pf] = sRow[((b * 20 + 10 + pf) << 10) + tid];
            da[pf] = dRow[((b * 20 + 2 * pf) << 10) + tid];
            db[pf] = dRow[((b * 20 + 2 * pf + 1) << 10) + tid];
        }
        #pragma unroll
        for (int it = 0; it < 10; ++it) {
            const int cur = it & 1;
            const float4 s4 = sc[cur], d04 = da[cur], d14 = db[cur];
            if (it + 2 < 10) {                        // depth-2 prefetch into freed slot
                sc[cur] = sRow[((b * 20 + 10 + it + 2) << 10) + tid];
                da[cur] = dRow[((b * 20 + 2 * (it + 2)) << 10) + tid];
                db[cur] = dRow[((b * 20 + 2 * (it + 2) + 1) << 10) + tid];
            }
            const float w = c_WS[it];
            const int l0 = tid << 2;                  // l = 4*tid + k, a = it
            const int r = (it << 12) + l0;
            unsigned key[4];
            float x1v[4], x2v[4];
            #pragma unroll
            for (int k = 0; k < 4; ++k) {
                const float d0 = (k == 0) ? d04.x : (k == 1) ? d04.y : (k == 2) ? d04.z : d04.w;
                const float d1 = (k == 0) ? d14.x : (k == 1) ? d14.y : (k == 2) ? d14.z : d14.w;
                float sv      = (k == 0) ? s4.x  : (k == 1) ? s4.y  : (k == 2) ? s4.z  : s4.w;
                const float ctr = (float)(8 * (l0 + k) + 4);
                const float pc = d0 * w + ctr;        // contract(off): mul then add, matches numpy
                const float pl = expf(d1) * w;
                const float x1 = fminf(fmaxf(pc - 0.5f * pl, 0.0f), 32767.0f);
                const float x2 = fminf(fmaxf(pc + 0.5f * pl, 0.0f), 32767.0f);
                if (x2 - x1 + 1.0f < 8.0f) sv = 0.0f;
                const unsigned u = __float_as_uint(sv);
                key[k] = (u & 0x80000000u) ? ~u : (u | 0x80000000u);  // ascending uint == float
                x1v[k] = x1; x2v[k] = x2;
            }
            // packed: reference flat index i = l*NA + a, inverted for descending tie-break
            unsigned long long p01[2], p23[2];
            #pragma unroll
            for (int k = 0; k < 4; ++k) {
                const unsigned long long pk = ((unsigned long long)key[k] << 32)
                    | (unsigned)(0xFFFFFFFFu - (unsigned)((l0 + k) * NA + it));
                if (k < 2) p01[k] = pk; else p23[k - 2] = pk;
            }
            *(ulonglong2*)&packed[b * NSEL + r]     = make_ulonglong2(p01[0], p01[1]);
            *(ulonglong2*)&packed[b * NSEL + r + 2] = make_ulonglong2(p23[0], p23[1]);
            *(float4*)&prop[b * NSEL + r]     = make_float4(x1v[0], x2v[0], x1v[1], x2v[1]);
            *(float4*)&prop[b * NSEL + r + 2] = make_float4(x1v[2], x2v[2], x1v[3], x2v[3]);
            #pragma unroll
            for (int k = 0; k < 4; ++k) {
                const unsigned kk = key[k] >> 16;
                atomicAdd(&hist[(((kk >> 1) & 31) << 10) | (kk >> 6)], 1u << ((kk & 1) << 4));
            }
        }
    }
    __syncthreads();

    // --- segment sums: thread t owns buckets [t*64, t*64+64) ---
    unsigned s = 0;
    #pragma unroll
    for (int c = 0; c < 32; ++c) {
        const unsigned h = hist[(c << 10) + tid];
        s += (h & 0xFFFFu) + (h >> 16);
    }
    // block suffix-scan over 1024 segment sums; find crossing segment
    {
        unsigned inc = s;
        #pragma unroll
        for (int d = 1; d < 64; d <<= 1) {
            unsigned u = (unsigned)__shfl_down((int)inc, d, 64);
            if (lane + d < 64) inc += u;
        }
        if (lane == 0) swsum[wv] = inc;
        __syncthreads();
        if (tid < 16) {
            unsigned t = swsum[tid];
            unsigned winc = t;
            #pragma unroll
            for (int d = 1; d < 16; d <<= 1) {
                unsigned u = (unsigned)__shfl_down((int)winc, d, 64);
                if (tid + d < 16) winc += u;
            }
            swsum[tid] = winc - t;               // sum of waves strictly after tid
        }
        __syncthreads();
        const unsigned glob = inc + swsum[wv];   // suffix including own segment
        if (glob >= (unsigned)PRE2 && (glob - s) < (unsigned)PRE2) { sSeg = tid; sAfter = glob - s; }
    }
    __syncthreads();

    // --- fine scan: wave 0 over crossing segment's 64 buckets ---
    if (wv == 0) {
        const int seg = sSeg;
        const unsigned h = hist[((lane >> 1) << 10) + seg];
        const unsigned v = (lane & 1) ? (h >> 16) : (h & 0xFFFFu);
        unsigned inc = v;
        #pragma unroll
        for (int d = 1; d < 64; d <<= 1) {
            unsigned u = (unsigned)__shfl_down((int)inc, d, 64);
            if (lane + d < 64) inc += u;
        }
        const unsigned glob = inc + sAfter;
        if (glob >= (unsigned)PRE2 && (glob - v) < (unsigned)PRE2)
            skmin = ((unsigned)((seg << 6) + lane)) << 16;
    }
    __syncthreads();
    const unsigned kmin = skmin;

    // --- pass 2: compact from L1/L2-hot packed (unordered; k_rank reconstructs order) ---
    const unsigned long long* pk = packed + b * NSEL;
    #pragma unroll
    for (int it = 0; it < NSEL / 2048; ++it) {
        const ulonglong2 pp = *(const ulonglong2*)&pk[(it * 1024 + tid) << 1];
        const bool pd0 = ((unsigned)(pp.x >> 32) >= kmin);
        const bool pd1 = ((unsigned)(pp.y >> 32) >= kmin);
        const unsigned long long m0 = __ballot(pd0);
        const unsigned long long m1 = __ballot(pd1);
        const int cnt = (int)(__popcll(m0) + __popcll(m1));
        int base = 0;
        if (cnt) {
            if (lane == 0) base = atomicAdd(&sCnt, cnt);
            base = __shfl(base, 0, 64);
            const unsigned long long below = (1ULL << lane) - 1ULL;
            if (pd0) {
                int pos = base + (int)__popcll(m0 & below);
                if (pos < CAND) cand[b * CAND + pos] = pp.x;
            }
            if (pd1) {
                int pos = base + (int)__popcll(m0) + (int)__popcll(m1 & below);
                if (pos < CAND) cand[b * CAND + pos] = pp.y;
            }
        }
    }
    __syncthreads();
    if (tid == 0) gcnt[b] = sCnt;
}

// ---------------- Kernel 2: rank-scatter, LDS-staged ----------------
// rank_i = #{j : key_j > key_i}: exact descending-sort position (keys unique).
__global__ __launch_bounds__(256) void k_rank(const unsigned long long* __restrict__ cand,
                                              const int* __restrict__ gcnt,
                                              const float2* __restrict__ prop,
                                              float2* __restrict__ srt) {
    __shared__ __align__(16) unsigned long long keys[CAND];   // 32 KB
    __shared__ unsigned part[4][64][4];                        // 4 KB partial ranks

    const int b = blockIdx.y;
    const int n0 = gcnt[b];
    const int n = n0 < CAND ? n0 : CAND;
    const int ib = blockIdx.x * 256;
    if (ib >= n) return;                       // uniform per block: safe before syncs

    const int tid = threadIdx.x;
    const int lane = tid & 63;
    const int wv = tid >> 6;
    const unsigned long long* cb = cand + b * CAND;

    // --- stage: coalesced bulk load, zero-pad to multiple of 8 (0 never outranks a real key) ---
    const int nP = (n + 7) & ~7;
    for (int j = tid; j < nP; j += 256)
        keys[j] = (j < n) ? cb[j] : 0ULL;
    __syncthreads();

    // --- my 4 candidates' keys (i = ib + 4*lane + c); reads past n are pad, guarded later ---
    const int i0 = ib + (lane << 2);
    const unsigned long long k0 = keys[i0 + 0];
    const unsigned long long k1 = keys[i0 + 1];
    const unsigned long long k2 = keys[i0 + 2];
    const unsigned long long k3 = keys[i0 + 3];

    // --- wave wv scans j-slice [wv*q, wv*q+q), q even -> 16B-aligned pair reads ---
    const int q = nP >> 2;
    const ulonglong2* keys2 = (const ulonglong2*)keys;
    const int p0 = (wv * q) >> 1;
    const int pn = q >> 1;
    unsigned r0 = 0, r1 = 0, r2 = 0, r3 = 0;
    #pragma unroll 4
    for (int p = 0; p < pn; ++p) {
        ulonglong2 kj = keys2[p0 + p];         // broadcast (all lanes same addr): conflict-free
        r0 += (kj.x > k0); r0 += (kj.y > k0);
        r1 += (kj.x > k1); r1 += (kj.y > k1);
        r2 += (kj.x > k2); r2 += (kj.y > k2);
        r3 += (kj.x > k3); r3 += (kj.y > k3);
    }
    part[wv][lane][0] = r0; part[wv][lane][1] = r1;
    part[wv][lane][2] = r2; part[wv][lane][3] = r3;
    __syncthreads();

    // --- combine partials, decode, gather box, scatter to rank position ---
    const int ig = ib + tid;
    if (ig < n) {
        const int l_ = tid >> 2, c_ = tid & 3;
        unsigned r = part[0][l_][c_] + part[1][l_][c_] + part[2][l_][c_] + part[3][l_][c_];
        if (r < PRE2) {
            unsigned long long k = keys[ig];
            unsigned idx_ = 0xFFFFFFFFu - (unsigned)k;
            unsigned a_ = idx_ % 10u, l2_ = idx_ / 10u;
            srt[b * PRE2 + r] = prop[b * NSEL + (a_ << 12) + l2_];
        }
    }
}

// ---------------- Kernel 3: COLUMN-major suppression mask over top-2048 ----------------
__global__ __launch_bounds__(256) void k_mask(const float2* __restrict__ srt,
                                              unsigned long long* __restrict__ maskT) {
    const int g  = blockIdx.x;          // wi in [4g, 4g+3]
    const int wj = blockIdx.y;
    const int b  = blockIdx.z;
    if (g * 4 > wj) return;             // whole group above diagonal

    __shared__ float2 lj[256];
    const int tid = threadIdx.x;
    lj[tid] = srt[b * PRE2 + (g << 8) + tid];    // suppressor candidates (4 words)
    __syncthreads();

    const int wi = (g << 2) + (tid >> 6);
    if (wi > wj) return;
    const int j = (wj << 6) + (tid & 63);

    float2 pj = srt[b * PRE2 + j];
    float ljn = pj.y - pj.x + 1.0f;
    unsigned long long bits = 0ULL;
    const int lbase = (tid >> 6) * 64;
    const int ibase = wi << 6;
    #pragma unroll 4
    for (int t = 0; t < 64; ++t) {
        float2 pv = lj[lbase + t];
        float inter = fminf(pj.y, pv.y) - fmaxf(pj.x, pv.x) + 1.0f;
        bool sup = false;
        if (inter > 0.0f) {
            float uni = ljn + (pv.y - pv.x + 1.0f) - inter;
            sup = (inter / uni) > 0.7f;          // IEEE div, same rounding as reference
        }
        if ((ibase + t < j) && sup) bits |= (1ULL << t);
    }
    maskT[(size_t)b * TWORDS + (size_t)((wj * (wj + 1) / 2) + wi) * 64 + (tid & 63)] = bits;
}

// ---------------- Kernel 4: single-wave greedy, DEPTH-4 column prefetch pipeline ----------------
// Fixed 16 KB stages (16 VMEM ops each), 4 LDS buffers, counted s_waitcnt vmcnt(48):
// 3 stages stay in flight so each has ~3 windows of compute+greedy to hide latency.
__global__ __launch_bounds__(64, 1) void k_reduce(const unsigned long long* __restrict__ maskT,
                                                  const float2* __restrict__ srt,
                                                  float* __restrict__ out) {
    const int b = blockIdx.x;
    const int lane = threadIdx.x;
    __shared__ unsigned long long colbuf[4][2048];   // 4 x 16 KB
    __shared__ unsigned long long Kl[32];            // kept bitset per window
    __shared__ int sKl[POST_NMS];

    const unsigned long long* mTb = maskT + (size_t)b * TWORDS;

    auto stage = [&](int wv, int buf) {              // fixed 16 KB stage (16 VMEM ops)
        const char* src = (const char*)(mTb + (size_t)(wv * (wv + 1) / 2) * 64) + lane * 16;
        char* dst = (char*)(&colbuf[buf][0]);
        #pragma unroll
        for (int k = 0; k < 16; ++k)
            gload_lds16(src + k * 1024, dst + k * 1024);
    };

    stage(0, 0); stage(1, 1); stage(2, 2); stage(3, 3);   // prologue: 64 ops in flight

    int kept = 0;
    bool done = false;

    for (int w = 0; w < 32 && !done; ++w) {
        // stages w+1..w+3 (48 ops) may stay outstanding; stage w must be complete
        asm volatile("s_waitcnt vmcnt(48)" ::: "memory");
        __builtin_amdgcn_sched_barrier(0);

        const unsigned long long* cw = &colbuf[w & 3][0];
        unsigned long long SUP = 0ULL;
        for (int wi = 0; wi < w; ++wi)
            SUP |= Kl[wi] & cw[(wi << 6) + lane];    // broadcast K read + per-lane col read
        unsigned long long x = cw[(w << 6) + lane];  // within-window suppressor column

        unsigned long long avail = ~__ballot(SUP != 0ULL);
        // retire all LDS reads of this buffer, pin x, THEN reuse the buffer slot for w+4
        asm volatile("s_waitcnt lgkmcnt(0)" ::: "memory");
        __builtin_amdgcn_sched_barrier(0);
        asm volatile("" : "+v"(x));
        {
            int nx = w + 4;
            stage(nx < 31 ? nx : 31, nx & 3);        // nx>=32: dummy re-stage keeps vmcnt invariant
        }

        unsigned long long keptw = 0ULL;
        while (avail) {
            int j = __ffsll((long long)avail) - 1;   // wave-uniform
            if (lane == 0) sKl[kept] = (w << 6) + j;
            kept++; keptw |= (1ULL << j);
            if (kept >= POST_NMS) { done = true; break; }
            unsigned long long supb = __ballot(((x >> j) & 1ULL) != 0ULL);
            avail &= ~supb;
            avail &= ~(1ULL << j);
        }
        if (lane == 0) Kl[w] = keptw;
    }

    __syncthreads();
    for (int t = lane; t < POST_NMS; t += 64) {
        float x1 = 0.0f, x2 = 0.0f;
        if (t < kept) {
            float2 pv = srt[b * PRE2 + sKl[t]];
            x1 = pv.x; x2 = pv.y;
        }
        float* o = out + (size_t)(b * POST_NMS + t) * 3;
        o[0] = (float)b; o[1] = x1; o[2] = x2;
    }
}

extern "C" void kernel_launch(void* const* d_in, const int* in_sizes, int n_in,
                              void* d_out, int out_size, void* d_ws, size_t ws_size,
                              hipStream_t stream) {
    const float* scores = (const float*)d_in[0];
    const float* deltas = (const float*)d_in[1];
    float* out = (float*)d_out;

    char* ws = (char*)d_ws;
    unsigned long long* packed = (unsigned long long*)ws;                   // 1,310,720 B
    float2* prop = (float2*)(ws + 1310720);                                 // 1,310,720 B
    float2* srt  = (float2*)(ws + 2621440);                                 //    65,536 B
    unsigned long long* maskT = (unsigned long long*)(ws + 2686976);        // 1,081,344 B
    unsigned long long* cand  = (unsigned long long*)(ws + 3768320);        //   131,072 B
    int* gcnt                 = (int*)(ws + 3899392);                       //        16 B

    k_select<<<NB, 1024, 0, stream>>>(scores, deltas, packed, prop, cand, gcnt);
    k_rank<<<dim3(CAND / 256, NB), 256, 0, stream>>>(cand, gcnt, prop, srt);
    k_mask<<<dim3(8, 32, NB), 256, 0, stream>>>(srt, maskT);
    k_reduce<<<NB, 64, 0, stream>>>(maskT, srt, out);
}

// Round 7
// 77.797 us; speedup vs baseline: 1.1225x; 1.1225x over previous
//
#include <hip/hip_runtime.h>
#include <stdint.h>

#pragma clang fp contract(off)

#define NA 10
#define LL 4096
#define NB 4
#define NSEL (LL * NA)        // 40960 proposals per image
#define PRE2 2048             // NMS candidate window (prefix-stable: 300 kept << 2048)
#define POST_NMS 300
#define CAND 4096             // candidate buffer (12-bit threshold overshoot bound)
#define NHB12 4096            // 12-bit-prefix histogram buckets
#define TWORDS 33792          // col-major mask words per image: 64 * sum_{w=0..31}(w+1)

__constant__ float c_WS[NA] = {16.f, 32.f, 40.f, 48.f, 64.f, 72.f, 80.f, 96.f, 112.f, 128.f};

// async global->LDS DMA: per-lane 16B from g (per-lane addr), lands at uniform dst + lane*16
__device__ inline void gload_lds16(const void* g, void* l) {
    __builtin_amdgcn_global_load_lds(
        (const __attribute__((address_space(1))) unsigned*)g,
        (__attribute__((address_space(3))) unsigned*)l, 16, 0, 0);
}

// ---------------- Kernel 1: decode (1 anchor-row per block) + 12-bit partial hist ----------------
// Round-6 post-mortem: fusing decode into the 4-block select serialized 163K decodes onto
// 4 CUs (+12us). And the r5 select core (two 320KB passes + 41K LDS atomics on 1 CU) was
// itself ~25-30us. Fix: decode stays WIDE (40 blocks, one per (image,anchor): c_WS[a]
// scalar, coalesced row reads) and each block emits a 4096-bucket (key>>20) partial hist
// to a DISTINCT global slot with plain stores -> no memset node, no global atomics.
// Exactness: the 12-bit threshold only needs survivors SUPERSET of top-2048 (k_rank
// reconstructs exact order); crossing-bucket width ~few hundred keys << CAND margin.
__global__ __launch_bounds__(1024) void k_prep(const float* __restrict__ scores,
                                               const float* __restrict__ deltas,
                                               unsigned long long* __restrict__ packed,
                                               float2* __restrict__ prop,
                                               unsigned* __restrict__ hpart) {
    __shared__ unsigned shist[NHB12];    // 16 KB
    const int tid = threadIdx.x;
    const int a = blockIdx.x;            // anchor = row
    const int b = blockIdx.y;

    #pragma unroll
    for (int i = 0; i < 4; ++i) shist[i * 1024 + tid] = 0;
    __syncthreads();

    const float4 s4  = ((const float4*)scores)[((b * 20 + 10 + a) << 10) + tid];
    const float4 d04 = ((const float4*)deltas)[((b * 20 + 2 * a) << 10) + tid];
    const float4 d14 = ((const float4*)deltas)[((b * 20 + 2 * a + 1) << 10) + tid];
    const float w = c_WS[a];
    const int l0 = tid << 2;             // l = 4*tid + k
    const int r = (a << 12) + l0;

    unsigned key[4];
    float x1v[4], x2v[4];
    #pragma unroll
    for (int k = 0; k < 4; ++k) {
        const float d0 = (k == 0) ? d04.x : (k == 1) ? d04.y : (k == 2) ? d04.z : d04.w;
        const float d1 = (k == 0) ? d14.x : (k == 1) ? d14.y : (k == 2) ? d14.z : d14.w;
        float sv      = (k == 0) ? s4.x  : (k == 1) ? s4.y  : (k == 2) ? s4.z  : s4.w;
        const float ctr = (float)(8 * (l0 + k) + 4);
        const float pc = d0 * w + ctr;   // contract(off): mul then add, matches numpy
        const float pl = expf(d1) * w;
        const float x1 = fminf(fmaxf(pc - 0.5f * pl, 0.0f), 32767.0f);
        const float x2 = fminf(fmaxf(pc + 0.5f * pl, 0.0f), 32767.0f);
        if (x2 - x1 + 1.0f < 8.0f) sv = 0.0f;
        const unsigned u = __float_as_uint(sv);
        key[k] = (u & 0x80000000u) ? ~u : (u | 0x80000000u);   // ascending uint == ascending float
        x1v[k] = x1; x2v[k] = x2;
    }
    // packed: reference flat index i = l*NA + a, inverted for descending tie-break
    const unsigned long long p0 = ((unsigned long long)key[0] << 32) | (unsigned)(0xFFFFFFFFu - (unsigned)((l0 + 0) * NA + a));
    const unsigned long long p1 = ((unsigned long long)key[1] << 32) | (unsigned)(0xFFFFFFFFu - (unsigned)((l0 + 1) * NA + a));
    const unsigned long long p2 = ((unsigned long long)key[2] << 32) | (unsigned)(0xFFFFFFFFu - (unsigned)((l0 + 2) * NA + a));
    const unsigned long long p3 = ((unsigned long long)key[3] << 32) | (unsigned)(0xFFFFFFFFu - (unsigned)((l0 + 3) * NA + a));
    *(ulonglong2*)&packed[b * NSEL + r]     = make_ulonglong2(p0, p1);
    *(ulonglong2*)&packed[b * NSEL + r + 2] = make_ulonglong2(p2, p3);
    *(float4*)&prop[b * NSEL + r]     = make_float4(x1v[0], x2v[0], x1v[1], x2v[1]);
    *(float4*)&prop[b * NSEL + r + 2] = make_float4(x1v[2], x2v[2], x1v[3], x2v[3]);

    #pragma unroll
    for (int k = 0; k < 4; ++k) atomicAdd(&shist[key[k] >> 20], 1u);
    __syncthreads();

    // plain-store partial hist to this block's own slot (no zeroing, no atomics)
    ((uint4*)&hpart[(b * 10 + a) << 12])[tid] = ((const uint4*)shist)[tid];
}

// ---------------- Kernel 2: sum partials -> exact crossing bucket -> compact ----------------
// One block per image. Thread t owns buckets [4t,4t+3] entirely in REGISTERS (quad sum of
// 10 partials = 160KB streamed reads, no LDS hist, no atomics). Suffix-scan over 1024
// thread-sums (proven shfl pattern) + r3's proven quad-crossing logic -> kmin = B<<20.
// Pass 2: single compact pass over packed with 4-deep unrolled register prefetch
// (statically indexed under full unroll: stays in VGPRs).
__global__ __launch_bounds__(1024, 1) void k_select(const unsigned long long* __restrict__ packed,
                                                    const unsigned* __restrict__ hpart,
                                                    unsigned long long* __restrict__ cand,
                                                    int* __restrict__ gcnt) {
    __shared__ unsigned swsum[16];
    __shared__ unsigned skmin;
    __shared__ int sCnt;

    const int tid = threadIdx.x;
    const int lane = tid & 63;
    const int wv = tid >> 6;
    const int b = blockIdx.x;

    if (tid == 0) sCnt = 0;

    // --- sum 10 anchor partials for my 4 buckets (registers only) ---
    uint4 h = make_uint4(0, 0, 0, 0);
    #pragma unroll
    for (int c = 0; c < 10; ++c) {
        const uint4 v = ((const uint4*)hpart)[((b * 10 + c) << 10) + tid];
        h.x += v.x; h.y += v.y; h.z += v.z; h.w += v.w;
    }
    const unsigned s = h.x + h.y + h.z + h.w;

    // --- block suffix-scan over 1024 quad-sums ---
    unsigned inc = s;
    #pragma unroll
    for (int d = 1; d < 64; d <<= 1) {
        unsigned u = (unsigned)__shfl_down((int)inc, d, 64);
        if (lane + d < 64) inc += u;
    }
    if (lane == 0) swsum[wv] = inc;
    __syncthreads();
    if (tid < 16) {
        unsigned t = swsum[tid];
        unsigned winc = t;
        #pragma unroll
        for (int d = 1; d < 16; d <<= 1) {
            unsigned u = (unsigned)__shfl_down((int)winc, d, 64);
            if (tid + d < 16) winc += u;
        }
        swsum[tid] = winc - t;               // sum of waves strictly after tid
    }
    __syncthreads();

    // --- crossing bucket within my quad (r3-proven pattern; buckets ascend x->w) ---
    {
        const unsigned glob = inc + swsum[wv];   // suffix including my 4 buckets
        const unsigned base = glob - s;          // strictly above my quad
        const unsigned t3 = base + h.w;
        const unsigned t2 = t3 + h.z;
        const unsigned t1 = t2 + h.y;
        const unsigned t0 = t1 + h.x;
        const unsigned bx = (unsigned)(tid << 2);
        if (t0 >= (unsigned)PRE2 && t0 - h.x < (unsigned)PRE2) skmin = (bx + 0) << 20;
        if (t1 >= (unsigned)PRE2 && t1 - h.y < (unsigned)PRE2) skmin = (bx + 1) << 20;
        if (t2 >= (unsigned)PRE2 && t2 - h.z < (unsigned)PRE2) skmin = (bx + 2) << 20;
        if (t3 >= (unsigned)PRE2 && t3 - h.w < (unsigned)PRE2) skmin = (bx + 3) << 20;
    }
    __syncthreads();
    const unsigned kmin = skmin;

    // --- compact pass (unordered; k_rank reconstructs exact descending order) ---
    const unsigned long long* pk = packed + b * NSEL;
    ulonglong2 pf[4];
    #pragma unroll
    for (int i = 0; i < 4; ++i) pf[i] = *(const ulonglong2*)&pk[((i * 1024 + tid) << 1)];
    #pragma unroll
    for (int it = 0; it < NSEL / 2048; ++it) {     // fully unrolled: pf[it&3] is static
        const ulonglong2 pp = pf[it & 3];
        if (it + 4 < NSEL / 2048)
            pf[it & 3] = *(const ulonglong2*)&pk[(((it + 4) * 1024 + tid) << 1)];
        const bool pd0 = ((unsigned)(pp.x >> 32) >= kmin);
        const bool pd1 = ((unsigned)(pp.y >> 32) >= kmin);
        const unsigned long long m0 = __ballot(pd0);
        const unsigned long long m1 = __ballot(pd1);
        const int cnt = (int)(__popcll(m0) + __popcll(m1));
        int base = 0;
        if (cnt) {
            if (lane == 0) base = atomicAdd(&sCnt, cnt);
            base = __shfl(base, 0, 64);
            const unsigned long long below = (1ULL << lane) - 1ULL;
            if (pd0) {
                int pos = base + (int)__popcll(m0 & below);
                if (pos < CAND) cand[b * CAND + pos] = pp.x;
            }
            if (pd1) {
                int pos = base + (int)__popcll(m0) + (int)__popcll(m1 & below);
                if (pos < CAND) cand[b * CAND + pos] = pp.y;
            }
        }
    }
    __syncthreads();
    if (tid == 0) gcnt[b] = sCnt;
}

// ---------------- Kernel 3: rank-scatter, LDS-staged ----------------
// rank_i = #{j : key_j > key_i}: exact descending-sort position (keys unique).
__global__ __launch_bounds__(256) void k_rank(const unsigned long long* __restrict__ cand,
                                              const int* __restrict__ gcnt,
                                              const float2* __restrict__ prop,
                                              float2* __restrict__ srt) {
    __shared__ __align__(16) unsigned long long keys[CAND];   // 32 KB
    __shared__ unsigned part[4][64][4];                        // 4 KB partial ranks

    const int b = blockIdx.y;
    const int n0 = gcnt[b];
    const int n = n0 < CAND ? n0 : CAND;
    const int ib = blockIdx.x * 256;
    if (ib >= n) return;                       // uniform per block: safe before syncs

    const int tid = threadIdx.x;
    const int lane = tid & 63;
    const int wv = tid >> 6;
    const unsigned long long* cb = cand + b * CAND;

    // --- stage: coalesced bulk load, zero-pad to multiple of 8 (0 never outranks a real key) ---
    const int nP = (n + 7) & ~7;
    for (int j = tid; j < nP; j += 256)
        keys[j] = (j < n) ? cb[j] : 0ULL;
    __syncthreads();

    // --- my 4 candidates' keys (i = ib + 4*lane + c); reads past n are pad, guarded later ---
    const int i0 = ib + (lane << 2);
    const unsigned long long k0 = keys[i0 + 0];
    const unsigned long long k1 = keys[i0 + 1];
    const unsigned long long k2 = keys[i0 + 2];
    const unsigned long long k3 = keys[i0 + 3];

    // --- wave wv scans j-slice [wv*q, wv*q+q), q even -> 16B-aligned pair reads ---
    const int q = nP >> 2;
    const ulonglong2* keys2 = (const ulonglong2*)keys;
    const int p0 = (wv * q) >> 1;
    const int pn = q >> 1;
    unsigned r0 = 0, r1 = 0, r2 = 0, r3 = 0;
    #pragma unroll 4
    for (int p = 0; p < pn; ++p) {
        ulonglong2 kj = keys2[p0 + p];         // broadcast (all lanes same addr): conflict-free
        r0 += (kj.x > k0); r0 += (kj.y > k0);
        r1 += (kj.x > k1); r1 += (kj.y > k1);
        r2 += (kj.x > k2); r2 += (kj.y > k2);
        r3 += (kj.x > k3); r3 += (kj.y > k3);
    }
    part[wv][lane][0] = r0; part[wv][lane][1] = r1;
    part[wv][lane][2] = r2; part[wv][lane][3] = r3;
    __syncthreads();

    // --- combine partials, decode, gather box, scatter to rank position ---
    const int ig = ib + tid;
    if (ig < n) {
        const int l_ = tid >> 2, c_ = tid & 3;
        unsigned r = part[0][l_][c_] + part[1][l_][c_] + part[2][l_][c_] + part[3][l_][c_];
        if (r < PRE2) {
            unsigned long long k = keys[ig];
            unsigned idx_ = 0xFFFFFFFFu - (unsigned)k;
            unsigned a_ = idx_ % 10u, l2_ = idx_ / 10u;
            srt[b * PRE2 + r] = prop[b * NSEL + (a_ << 12) + l2_];
        }
    }
}

// ---------------- Kernel 4: COLUMN-major suppression mask over top-2048 ----------------
__global__ __launch_bounds__(256) void k_mask(const float2* __restrict__ srt,
                                              unsigned long long* __restrict__ maskT) {
    const int g  = blockIdx.x;          // wi in [4g, 4g+3]
    const int wj = blockIdx.y;
    const int b  = blockIdx.z;
    if (g * 4 > wj) return;             // whole group above diagonal

    __shared__ float2 lj[256];
    const int tid = threadIdx.x;
    lj[tid] = srt[b * PRE2 + (g << 8) + tid];    // suppressor candidates (4 words)
    __syncthreads();

    const int wi = (g << 2) + (tid >> 6);
    if (wi > wj) return;
    const int j = (wj << 6) + (tid & 63);

    float2 pj = srt[b * PRE2 + j];
    float ljn = pj.y - pj.x + 1.0f;
    unsigned long long bits = 0ULL;
    const int lbase = (tid >> 6) * 64;
    const int ibase = wi << 6;
    #pragma unroll 4
    for (int t = 0; t < 64; ++t) {
        float2 pv = lj[lbase + t];
        float inter = fminf(pj.y, pv.y) - fmaxf(pj.x, pv.x) + 1.0f;
        bool sup = false;
        if (inter > 0.0f) {
            float uni = ljn + (pv.y - pv.x + 1.0f) - inter;
            sup = (inter / uni) > 0.7f;          // IEEE div, same rounding as reference
        }
        if ((ibase + t < j) && sup) bits |= (1ULL << t);
    }
    maskT[(size_t)b * TWORDS + (size_t)((wj * (wj + 1) / 2) + wi) * 64 + (tid & 63)] = bits;
}

// ---------------- Kernel 5: single-wave greedy, DEPTH-4 column prefetch pipeline ----------------
// Fixed 16 KB stages (16 VMEM ops each), 4 LDS buffers, counted s_waitcnt vmcnt(48):
// 3 stages stay in flight so each has ~3 windows of compute+greedy to hide latency.
__global__ __launch_bounds__(64, 1) void k_reduce(const unsigned long long* __restrict__ maskT,
                                                  const float2* __restrict__ srt,
                                                  float* __restrict__ out) {
    const int b = blockIdx.x;
    const int lane = threadIdx.x;
    __shared__ unsigned long long colbuf[4][2048];   // 4 x 16 KB
    __shared__ unsigned long long Kl[32];            // kept bitset per window
    __shared__ int sKl[POST_NMS];

    const unsigned long long* mTb = maskT + (size_t)b * TWORDS;

    auto stage = [&](int wv, int buf) {              // fixed 16 KB stage (16 VMEM ops)
        const char* src = (const char*)(mTb + (size_t)(wv * (wv + 1) / 2) * 64) + lane * 16;
        char* dst = (char*)(&colbuf[buf][0]);
        #pragma unroll
        for (int k = 0; k < 16; ++k)
            gload_lds16(src + k * 1024, dst + k * 1024);
    };

    stage(0, 0); stage(1, 1); stage(2, 2); stage(3, 3);   // prologue: 64 ops in flight

    int kept = 0;
    bool done = false;

    for (int w = 0; w < 32 && !done; ++w) {
        // stages w+1..w+3 (48 ops) may stay outstanding; stage w must be complete
        asm volatile("s_waitcnt vmcnt(48)" ::: "memory");
        __builtin_amdgcn_sched_barrier(0);

        const unsigned long long* cw = &colbuf[w & 3][0];
        unsigned long long SUP = 0ULL;
        for (int wi = 0; wi < w; ++wi)
            SUP |= Kl[wi] & cw[(wi << 6) + lane];    // broadcast K read + per-lane col read
        unsigned long long x = cw[(w << 6) + lane];  // within-window suppressor column

        unsigned long long avail = ~__ballot(SUP != 0ULL);
        // retire all LDS reads of this buffer, pin x, THEN reuse the buffer slot for w+4
        asm volatile("s_waitcnt lgkmcnt(0)" ::: "memory");
        __builtin_amdgcn_sched_barrier(0);
        asm volatile("" : "+v"(x));
        {
            int nx = w + 4;
            stage(nx < 31 ? nx : 31, nx & 3);        // nx>=32: dummy re-stage keeps vmcnt invariant
        }

        unsigned long long keptw = 0ULL;
        while (avail) {
            int j = __ffsll((long long)avail) - 1;   // wave-uniform
            if (lane == 0) sKl[kept] = (w << 6) + j;
            kept++; keptw |= (1ULL << j);
            if (kept >= POST_NMS) { done = true; break; }
            unsigned long long supb = __ballot(((x >> j) & 1ULL) != 0ULL);
            avail &= ~supb;
            avail &= ~(1ULL << j);
        }
        if (lane == 0) Kl[w] = keptw;
    }

    __syncthreads();
    for (int t = lane; t < POST_NMS; t += 64) {
        float x1 = 0.0f, x2 = 0.0f;
        if (t < kept) {
            float2 pv = srt[b * PRE2 + sKl[t]];
            x1 = pv.x; x2 = pv.y;
        }
        float* o = out + (size_t)(b * POST_NMS + t) * 3;
        o[0] = (float)b; o[1] = x1; o[2] = x2;
    }
}

extern "C" void kernel_launch(void* const* d_in, const int* in_sizes, int n_in,
                              void* d_out, int out_size, void* d_ws, size_t ws_size,
                              hipStream_t stream) {
    const float* scores = (const float*)d_in[0];
    const float* deltas = (const float*)d_in[1];
    float* out = (float*)d_out;

    char* ws = (char*)d_ws;
    unsigned long long* packed = (unsigned long long*)ws;                   // 1,310,720 B
    float2* prop = (float2*)(ws + 1310720);                                 // 1,310,720 B
    float2* srt  = (float2*)(ws + 2621440);                                 //    65,536 B
    unsigned long long* maskT = (unsigned long long*)(ws + 2686976);        // 1,081,344 B
    unsigned long long* cand  = (unsigned long long*)(ws + 3768320);        //   131,072 B
    int* gcnt                 = (int*)(ws + 3899392);                       //        16 B
    unsigned* hpart           = (unsigned*)(ws + 3899408);                  //   655,360 B (40 x 16KB partials)

    k_prep<<<dim3(NA, NB), 1024, 0, stream>>>(scores, deltas, packed, prop, hpart);
    k_select<<<NB, 1024, 0, stream>>>(packed, hpart, cand, gcnt);
    k_rank<<<dim3(CAND / 256, NB), 256, 0, stream>>>(cand, gcnt, prop, srt);
    k_mask<<<dim3(8, 32, NB), 256, 0, stream>>>(srt, maskT);
    k_reduce<<<NB, 64, 0, stream>>>(maskT, srt, out);
}